// Round 1
// baseline (97.711 us; speedup 1.0000x reference)
//
#include <hip/hip_runtime.h>
#include <hip/hip_bf16.h>

// PolicyGradientLoss: B=64, S=512, A=4096
// out = mean_b( -sum_s[(logits[b,s,act] - lse(logits[b,s,:])) * (1-term[b,s])]
//               * sum_s rewards[b,s] )
// Memory-bound on the 512 MiB logits read (one pass, online in registers).

#define PG_B 64
#define PG_S 512
#define PG_A 4096

// ---------------- Kernel A: per-row masked chosen log-prob ----------------
// One 256-thread block per (b,s) row. Each thread: 16 floats (4x float4,
// coalesced with stride 256 float4s). Two register passes: max, then sum-exp.
__global__ __launch_bounds__(256) void pg_row_lse(
    const float* __restrict__ logits,
    const int* __restrict__ actions,
    const int* __restrict__ terminals,
    float* __restrict__ chosen_out)  // [B*S]
{
    const int row = blockIdx.x;                 // b*S + s
    const float* __restrict__ rp = logits + (size_t)row * PG_A;
    const float4* __restrict__ rp4 = (const float4*)rp;

    const int t = threadIdx.x;
    const int lane = t & 63;
    const int wave = t >> 6;

    // ---- load 16 floats ----
    float4 v0 = rp4[t];
    float4 v1 = rp4[t + 256];
    float4 v2 = rp4[t + 512];
    float4 v3 = rp4[t + 768];

    // ---- per-thread max over 16 ----
    float m = fmaxf(fmaxf(fmaxf(v0.x, v0.y), fmaxf(v0.z, v0.w)),
                    fmaxf(fmaxf(v1.x, v1.y), fmaxf(v1.z, v1.w)));
    m = fmaxf(m, fmaxf(fmaxf(v2.x, v2.y), fmaxf(v2.z, v2.w)));
    m = fmaxf(m, fmaxf(fmaxf(v3.x, v3.y), fmaxf(v3.z, v3.w)));

    // ---- wave reduce max (64 lanes) ----
    #pragma unroll
    for (int off = 32; off > 0; off >>= 1)
        m = fmaxf(m, __shfl_xor(m, off));

    // ---- cross-wave max via LDS (4 waves) ----
    __shared__ float red_m[4];
    __shared__ float red_s[4];
    if (lane == 0) red_m[wave] = m;
    __syncthreads();
    m = fmaxf(fmaxf(red_m[0], red_m[1]), fmaxf(red_m[2], red_m[3]));

    // ---- per-thread sum of exp(x - m) from registers ----
    float s = __expf(v0.x - m) + __expf(v0.y - m) + __expf(v0.z - m) + __expf(v0.w - m);
    s += __expf(v1.x - m) + __expf(v1.y - m) + __expf(v1.z - m) + __expf(v1.w - m);
    s += __expf(v2.x - m) + __expf(v2.y - m) + __expf(v2.z - m) + __expf(v2.w - m);
    s += __expf(v3.x - m) + __expf(v3.y - m) + __expf(v3.z - m) + __expf(v3.w - m);

    // ---- wave reduce sum ----
    #pragma unroll
    for (int off = 32; off > 0; off >>= 1)
        s += __shfl_xor(s, off);

    if (lane == 0) red_s[wave] = s;
    __syncthreads();

    if (t == 0) {
        float ssum = red_s[0] + red_s[1] + red_s[2] + red_s[3];
        float lse = m + __logf(ssum);
        int   act = actions[row];
        float ch  = rp[act];                 // L1/L2-hot: row was just read
        float keep = 1.0f - (float)terminals[row];
        chosen_out[row] = (ch - lse) * keep;
    }
}

// ---------------- Kernel B: finalize (deterministic, single block) -------
// 512 threads = 8 waves. Each wave handles 8 batch rows; 64 lanes x 8 elems
// per row. Fixed reduction order -> deterministic output across replays.
__global__ __launch_bounds__(512) void pg_finalize(
    const float* __restrict__ chosen,    // [B*S]
    const float* __restrict__ rewards,   // [B*S]
    float* __restrict__ out)             // [1]
{
    __shared__ float lossb[PG_B];
    const int t = threadIdx.x;
    const int lane = t & 63;
    const int wave = t >> 6;

    #pragma unroll
    for (int i = 0; i < PG_B / 8; ++i) {
        const int b = wave * (PG_B / 8) + i;
        const float* cb = chosen  + (size_t)b * PG_S;
        const float* rb = rewards + (size_t)b * PG_S;
        float cs = 0.0f, rs = 0.0f;
        #pragma unroll
        for (int j = 0; j < PG_S / 64; ++j) {
            const int s = lane + 64 * j;
            cs += cb[s];
            rs += rb[s];
        }
        #pragma unroll
        for (int off = 32; off > 0; off >>= 1) {
            cs += __shfl_xor(cs, off);
            rs += __shfl_xor(rs, off);
        }
        if (lane == 0) lossb[b] = -cs * rs;
    }
    __syncthreads();

    if (t < 64) {
        float v = lossb[t];
        #pragma unroll
        for (int off = 32; off > 0; off >>= 1)
            v += __shfl_xor(v, off);
        if (t == 0) out[0] = v * (1.0f / (float)PG_B);
    }
}

extern "C" void kernel_launch(void* const* d_in, const int* in_sizes, int n_in,
                              void* d_out, int out_size, void* d_ws, size_t ws_size,
                              hipStream_t stream) {
    // setup_inputs() dict order: actions, logits, rewards, terminals
    const int*   actions   = (const int*)d_in[0];
    const float* logits    = (const float*)d_in[1];
    const float* rewards   = (const float*)d_in[2];
    const int*   terminals = (const int*)d_in[3];
    float* out = (float*)d_out;

    float* chosen = (float*)d_ws;   // B*S floats = 128 KiB scratch

    pg_row_lse<<<PG_B * PG_S, 256, 0, stream>>>(logits, actions, terminals, chosen);
    pg_finalize<<<1, 512, 0, stream>>>(chosen, rewards, out);
}